// Round 2
// baseline (833.224 us; speedup 1.0000x reference)
//
#include <hip/hip_runtime.h>
#include <cfloat>
#include <cmath>

#define NP 10000
#define NG 1000
#define NC 80
#define LMAX 6

__device__ __forceinline__ bool lexless(float av, int ai, float bv, int bi) {
    return (av < bv) || (av == bv && ai < bi);
}

// ---------------------------------------------------------------------------
// Kernel 1: per-(pred,class) focal cls table (column-major [NC][NP]) + per-pred
// validity (any in_boxes | any in_centers).
// Blocks [0, 3125): cls table. Blocks [3125, 3165): validity.
// ---------------------------------------------------------------------------
__global__ __launch_bounds__(256) void k_clsvalid(const float* __restrict__ logits,
        const float* __restrict__ pb, const float* __restrict__ gb,
        float* __restrict__ clsval, int* __restrict__ valid)
{
    __shared__ float sgb[NG * 4];
    int b = blockIdx.x;
    const int CLS_BLOCKS = (NC * NP) / 256;   // 3125
    if (b < CLS_BLOCKS) {
        int tid = b * 256 + threadIdx.x;      // tid = c*NP + i
        int c = tid / NP;
        int i = tid - c * NP;
        float x = logits[i * NC + c];
        float p = 1.0f / (1.0f + expf(-x));
        float neg = -log1pf(-(p - 1e-12f)) * 0.75f * (p * p);
        float om = 1.0f - p;
        float pos = -logf(p + 1e-12f) * 0.25f * (om * om);
        clsval[tid] = (pos - neg) * 2.0f;     // * CLS_W
    } else {
        for (int t = threadIdx.x; t < NG * 4; t += 256) sgb[t] = gb[t];
        __syncthreads();
        int i = (b - CLS_BLOCKS) * 256 + threadIdx.x;
        if (i < NP) {
            float p0 = pb[i*4+0], p1 = pb[i*4+1], p2 = pb[i*4+2], p3 = pb[i*4+3];
            float pcx = (p0 + p2) * 0.5f, pcy = (p1 + p3) * 0.5f;
            int vb = 0, vc = 0;
            for (int j = 0; j < NG; j++) {
                float g0 = sgb[j*4+0], g1 = sgb[j*4+1], g2 = sgb[j*4+2], g3 = sgb[j*4+3];
                vb |= (pcx > g0 && pcx < g2 && pcy > g1 && pcy < g3) ? 1 : 0;
                float gcx = (g0 + g2) * 0.5f, gcy = (g1 + g3) * 0.5f;
                float gw = g2 - g0, gh = g3 - g1;
                vc |= (pcx > gcx - 2.5f * gw && pcx < gcx + 2.5f * gw &&
                       pcy > gcy - 2.5f * gh && pcy < gcy + 2.5f * gh) ? 1 : 0;
            }
            valid[i] = vb | vc;
        }
    }
}

// ---------------------------------------------------------------------------
// Kernel 2: block per gt j. Computes cost column (column-major), zeroes mm
// column, block-wide top-5 min-cost (lexicographic, = lax.top_k(-cost.T)) and
// top-5 max iou (values; = lax.top_k(ious.T)), then sets initial mm bits for
// t < dynamic_k.  Block 0 thread 0 also zeroes the iteration flags.
// ---------------------------------------------------------------------------
__global__ __launch_bounds__(256) void k_cost(
        const float* __restrict__ pb, const float* __restrict__ gb,
        const int* __restrict__ glab, const float* __restrict__ clsval,
        const int* __restrict__ valid, const int* __restrict__ imgw,
        const int* __restrict__ imgh, float* __restrict__ cost,
        unsigned char* __restrict__ mm, int* __restrict__ flags)
{
    __shared__ float s_cv[256 * 6];
    __shared__ int   s_ci[256 * 6];
    __shared__ float s_iv[256 * 6];

    int j = blockIdx.x;
    float fw = (float)imgw[0], fh = (float)imgh[0];
    float g0 = gb[j*4+0], g1 = gb[j*4+1], g2 = gb[j*4+2], g3 = gb[j*4+3];
    int lbl = glab[j];
    float area_g = (g2 - g0) * (g3 - g1);
    float gcx = (g0 + g2) * 0.5f, gcy = (g1 + g3) * 0.5f;
    float gw = g2 - g0, gh = g3 - g1;
    float cb0 = gcx - 2.5f * gw, cb1 = gcy - 2.5f * gh;
    float cb2 = gcx + 2.5f * gw, cb3 = gcy + 2.5f * gh;
    float G0 = g0 / fw, G1 = g1 / fh, G2 = g2 / fw, G3 = g3 / fh;
    const float* clscol = clsval + (size_t)lbl * NP;
    float* ccol = cost + (size_t)j * NP;
    unsigned char* mcol = mm + (size_t)j * NP;

    float cv[5]; int ci[5]; float iv[5];
#pragma unroll
    for (int t = 0; t < 5; t++) { cv[t] = FLT_MAX; ci[t] = 0x7fffffff; iv[t] = -1.0f; }

    for (int i = threadIdx.x; i < NP; i += 256) {
        float p0 = pb[i*4+0], p1 = pb[i*4+1], p2 = pb[i*4+2], p3 = pb[i*4+3];
        float area_p = (p2 - p0) * (p3 - p1);
        float wx = fminf(p2, g2) - fmaxf(p0, g0); wx = fmaxf(wx, 0.0f);
        float wy = fminf(p3, g3) - fmaxf(p1, g1); wy = fmaxf(wy, 0.0f);
        float inter = wx * wy;
        float uni = area_p + area_g - inter;
        float iou = inter / fmaxf(uni, 1e-12f);
        float ex = fmaxf(p2, g2) - fminf(p0, g0); ex = fmaxf(ex, 0.0f);
        float ey = fmaxf(p3, g3) - fminf(p1, g1); ey = fmaxf(ey, 0.0f);
        float enc = ex * ey;
        float giou = iou - (enc - uni) / fmaxf(enc, 1e-12f);

        float l1 = ((fabsf(p0 / fw - G0) + fabsf(p1 / fh - G1))
                    + fabsf(p2 / fw - G2)) + fabsf(p3 / fh - G3);
        float cc = clscol[i] + l1 * 5.0f;       // cls_cost + l1_cost
        cc = cc + (-giou * 2.0f);               // + iou_cost
        float pcx = (p0 + p2) * 0.5f, pcy = (p1 + p3) * 0.5f;
        bool inb = (pcx > g0 && pcx < g2 && pcy > g1 && pcy < g3);
        bool inc = (pcx > cb0 && pcx < cb2 && pcy > cb1 && pcy < cb3);
        cc = cc + ((inb && inc) ? 0.0f : 100.0f);
        cc = cc + (valid[i] ? 0.0f : 10000.0f);

        ccol[i] = cc;
        mcol[i] = 0;

        // per-thread top-5 min cost (lexicographic value,index)
        if (lexless(cc, i, cv[4], ci[4])) {
            cv[4] = cc; ci[4] = i;
#pragma unroll
            for (int t = 4; t > 0; t--) {
                if (lexless(cv[t], ci[t], cv[t-1], ci[t-1])) {
                    float tv = cv[t]; cv[t] = cv[t-1]; cv[t-1] = tv;
                    int tx = ci[t]; ci[t] = ci[t-1]; ci[t-1] = tx;
                }
            }
        }
        // per-thread top-5 max iou (values only; sum is tie-insensitive)
        if (iou > iv[4]) {
            iv[4] = iou;
#pragma unroll
            for (int t = 4; t > 0; t--) {
                if (iv[t] > iv[t-1]) { float tv = iv[t]; iv[t] = iv[t-1]; iv[t-1] = tv; }
            }
        }
    }

    int base = threadIdx.x * 6;
#pragma unroll
    for (int t = 0; t < 5; t++) { s_cv[base+t] = cv[t]; s_ci[base+t] = ci[t]; s_iv[base+t] = iv[t]; }
    s_cv[base+5] = FLT_MAX; s_ci[base+5] = 0x7fffffff; s_iv[base+5] = -2.0f;
    __syncthreads();

    for (int w = 128; w > 0; w >>= 1) {
        if (threadIdx.x < (unsigned)w) {
            int a = threadIdx.x * 6, bb = (threadIdx.x + w) * 6;
            float ov[5]; int oi[5]; float og[5];
            int pa = a, pbp = bb;
#pragma unroll
            for (int t = 0; t < 5; t++) {
                float A = s_cv[pa], B = s_cv[pbp];
                int Ai = s_ci[pa], Bi = s_ci[pbp];
                bool tA = (A < B) || (A == B && Ai <= Bi);
                if (tA) { ov[t] = A; oi[t] = Ai; pa++; } else { ov[t] = B; oi[t] = Bi; pbp++; }
            }
            int qa = a, qb = bb;
#pragma unroll
            for (int t = 0; t < 5; t++) {
                float A = s_iv[qa], B = s_iv[qb];
                if (A >= B) { og[t] = A; qa++; } else { og[t] = B; qb++; }
            }
#pragma unroll
            for (int t = 0; t < 5; t++) { s_cv[a+t] = ov[t]; s_ci[a+t] = oi[t]; s_iv[a+t] = og[t]; }
        }
        __syncthreads();
    }

    if (threadIdx.x == 0) {
        float s = (((s_iv[0] + s_iv[1]) + s_iv[2]) + s_iv[3]) + s_iv[4];
        int dk = (int)s;                 // astype(int32): truncation
        if (dk < 1) dk = 1;              // maximum(.,1); dk <= 5 since iou<=1
        for (int t = 0; t < dk; t++) mcol[s_ci[t]] = 1;
        if (j == 0) { for (int t = 0; t < 2 * LMAX; t++) flags[t] = 0; }
    }
}

// ---------------------------------------------------------------------------
// Kernel 3: prior fix. Rows with >1 assignment collapse to one_hot(argmin cost).
// ---------------------------------------------------------------------------
__global__ __launch_bounds__(256) void k_prior(const float* __restrict__ cost,
        unsigned char* __restrict__ mm, int* __restrict__ prior)
{
    int i = blockIdx.x * 256 + threadIdx.x;
    if (i >= NP) return;
    int cnt = 0;
    for (int j = 0; j < NG; j++) cnt += mm[(size_t)j * NP + i];
    if (cnt > 1) {
        prior[i] = 1;
        float best = FLT_MAX; int bj = 0;
        for (int j = 0; j < NG; j++) {
            float c = cost[(size_t)j * NP + i];
            if (c < best) { best = c; bj = j; }   // first-index argmin
        }
        for (int j = 0; j < NG; j++) mm[(size_t)j * NP + i] = (j == bj) ? 1 : 0;
    } else {
        prior[i] = 0;
    }
}

// ---------------------------------------------------------------------------
// While-loop body, split into 3 kernels per iteration (flags make converged
// iterations no-ops; flag monotonically falls so prev-flag early-exit is safe).
// iterA: colsum -> flag_unmatched; rowsum -> +1e5 inflation of matched rows
//        (harmless when loop inactive: cost is never consumed again); pickcnt=0.
// ---------------------------------------------------------------------------
__global__ __launch_bounds__(256) void k_iterA(const unsigned char* __restrict__ mm,
        float* __restrict__ cost, int* __restrict__ colsum,
        int* __restrict__ pickcnt, int* __restrict__ flags, int t)
{
    if (t > 0 && flags[2 * (t - 1)] == 0) return;
    __shared__ int red[256];
    int b = blockIdx.x;
    if (b < NG) {
        const unsigned char* col = mm + (size_t)b * NP;
        int s = 0;
        for (int i = threadIdx.x; i < NP; i += 256) s += col[i];
        red[threadIdx.x] = s; __syncthreads();
        for (int w = 128; w > 0; w >>= 1) {
            if (threadIdx.x < (unsigned)w) red[threadIdx.x] += red[threadIdx.x + w];
            __syncthreads();
        }
        if (threadIdx.x == 0) { colsum[b] = red[0]; if (red[0] == 0) flags[2 * t] = 1; }
    } else {
        int i = (b - NG) * 256 + threadIdx.x;
        if (i < NP) {
            pickcnt[i] = 0;
            int cnt = 0;
            for (int j = 0; j < NG; j++) cnt += mm[(size_t)j * NP + i];
            if (cnt > 0)
                for (int j = 0; j < NG; j++) cost[(size_t)j * NP + i] += 100000.0f;
        }
    }
}

// iterB: each unmatched column picks argmin_i c (first-index), sets mm bit,
// detects multi-pick collisions -> flag_multi (== any(rowsum>1) after update).
__global__ __launch_bounds__(256) void k_iterB(const float* __restrict__ cost,
        unsigned char* __restrict__ mm, const int* __restrict__ colsum,
        int* __restrict__ pickcnt, int* __restrict__ flags, int t)
{
    if (flags[2 * t] == 0) return;
    int j = blockIdx.x;
    if (colsum[j] != 0) return;
    __shared__ float rv[256]; __shared__ int ri[256];
    const float* col = cost + (size_t)j * NP;
    float best = FLT_MAX; int bi = 0x7fffffff;
    for (int i = threadIdx.x; i < NP; i += 256) {
        float c = col[i];
        if (lexless(c, i, best, bi)) { best = c; bi = i; }
    }
    rv[threadIdx.x] = best; ri[threadIdx.x] = bi; __syncthreads();
    for (int w = 128; w > 0; w >>= 1) {
        if (threadIdx.x < (unsigned)w) {
            float ov = rv[threadIdx.x + w]; int oi = ri[threadIdx.x + w];
            if (lexless(ov, oi, rv[threadIdx.x], ri[threadIdx.x])) {
                rv[threadIdx.x] = ov; ri[threadIdx.x] = oi;
            }
        }
        __syncthreads();
    }
    if (threadIdx.x == 0) {
        int pos = ri[0];
        mm[(size_t)j * NP + pos] = 1;
        int old = atomicAdd(&pickcnt[pos], 1);
        if (old >= 1) flags[2 * t + 1] = 1;
    }
}

// iterC: m_fix — when flag_multi, prior rows rewritten to one_hot(argmin of the
// *current inflated* cost) exactly as the reference.
__global__ __launch_bounds__(256) void k_iterC(const float* __restrict__ cost,
        unsigned char* __restrict__ mm, const int* __restrict__ prior,
        const int* __restrict__ flags, int t)
{
    if (flags[2 * t] == 0 || flags[2 * t + 1] == 0) return;
    int i = blockIdx.x * 256 + threadIdx.x;
    if (i >= NP || !prior[i]) return;
    float best = FLT_MAX; int bj = 0;
    for (int j = 0; j < NG; j++) {
        float c = cost[(size_t)j * NP + i];
        if (c < best) { best = c; bj = j; }
    }
    for (int j = 0; j < NG; j++) mm[(size_t)j * NP + i] = (j == bj) ? 1 : 0;
}

// ---------------------------------------------------------------------------
// Final: fg_mask = rowsum>0 ; matched = first j with mm==1 (argmax semantics),
// masked to 0. Output buffer is INT32 (reference returns bool+int32; harness
// reads the buffer as np.int32 — R0's absmax 1065353215 == float1.0-bits - 1
// proved this).
// ---------------------------------------------------------------------------
__global__ __launch_bounds__(256) void k_final(const unsigned char* __restrict__ mm,
        int* __restrict__ out)
{
    int i = blockIdx.x * 256 + threadIdx.x;
    if (i >= NP) return;
    int first = -1, cnt = 0;
    for (int j = 0; j < NG; j++) {
        if (mm[(size_t)j * NP + i]) { cnt++; if (first < 0) first = j; }
    }
    out[i] = (cnt > 0) ? 1 : 0;
    out[NP + i] = (cnt > 0) ? first : 0;
}

extern "C" void kernel_launch(void* const* d_in, const int* in_sizes, int n_in,
                              void* d_out, int out_size, void* d_ws, size_t ws_size,
                              hipStream_t stream)
{
    (void)in_sizes; (void)n_in; (void)out_size; (void)ws_size;
    const float* logits = (const float*)d_in[0];
    const float* pboxes = (const float*)d_in[1];
    const float* gboxes = (const float*)d_in[2];
    const int*   glab   = (const int*)d_in[3];
    const int*   imgh   = (const int*)d_in[4];
    const int*   imgw   = (const int*)d_in[5];
    int* out = (int*)d_out;

    char* w = (char*)d_ws;
    float* cost            = (float*)(w);                  // 40,000,000 B
    float* clsval          = (float*)(w + 40000000);       //  3,200,000 B
    unsigned char* mm      = (unsigned char*)(w + 43200000); // 10,000,000 B
    int* valid             = (int*)(w + 53200000);         //     40,000 B
    int* prior             = (int*)(w + 53240000);         //     40,000 B
    int* colsum            = (int*)(w + 53280000);         //      4,000 B
    int* pickcnt           = (int*)(w + 53284000);         //     40,000 B
    int* flags             = (int*)(w + 53324000);         //         48 B

    hipLaunchKernelGGL(k_clsvalid, dim3(3165), dim3(256), 0, stream,
                       logits, pboxes, gboxes, clsval, valid);
    hipLaunchKernelGGL(k_cost, dim3(NG), dim3(256), 0, stream,
                       pboxes, gboxes, glab, clsval, valid, imgw, imgh,
                       cost, mm, flags);
    hipLaunchKernelGGL(k_prior, dim3(40), dim3(256), 0, stream, cost, mm, prior);
    for (int t = 0; t < LMAX; t++) {
        hipLaunchKernelGGL(k_iterA, dim3(NG + 40), dim3(256), 0, stream,
                           mm, cost, colsum, pickcnt, flags, t);
        hipLaunchKernelGGL(k_iterB, dim3(NG), dim3(256), 0, stream,
                           cost, mm, colsum, pickcnt, flags, t);
        hipLaunchKernelGGL(k_iterC, dim3(40), dim3(256), 0, stream,
                           cost, mm, prior, flags, t);
    }
    hipLaunchKernelGGL(k_final, dim3(40), dim3(256), 0, stream, mm, out);
}

// Round 3
// 463.914 us; speedup vs baseline: 1.7961x; 1.7961x over previous
//
#include <hip/hip_runtime.h>
#include <cfloat>
#include <cmath>

#define NP 10000
#define NG 1000
#define NC 80
#define LMAX 6

// scal[] layout: [0..2*LMAX-1] flags (2t = body-active, 2t+1 unused),
// [12] anymulti (persistent), [13] numUnmatched, [14] nprior
#define S_MULTI 12
#define S_NUNM  13
#define S_NPRI  14

__device__ __forceinline__ bool lexless(float av, int ai, float bv, int bi) {
    return (av < bv) || (av == bv && ai < bi);
}

// Exact sequential +1e5 inflation (reference adds 1e5 once per loop iteration).
__device__ __forceinline__ float inflate(float c, int k) {
    for (int q = 0; q < k; q++) c += 100000.0f;
    return c;
}

struct GtConst {
    float g0, g1, g2, g3, area_g;
    float cb0, cb1, cb2, cb3;
    float G0, G1, G2, G3;
};

// All cost-affecting arithmetic with contraction OFF so every kernel that
// recomputes cost(i,j) gets bit-identical values.
__device__ __forceinline__ void make_gt(const float4 gv, float fw, float fh, GtConst& G) {
#pragma clang fp contract(off)
    float g0 = gv.x, g1 = gv.y, g2 = gv.z, g3 = gv.w;
    G.g0 = g0; G.g1 = g1; G.g2 = g2; G.g3 = g3;
    G.area_g = (g2 - g0) * (g3 - g1);
    float gcx = (g0 + g2) * 0.5f, gcy = (g1 + g3) * 0.5f;
    float gw = g2 - g0, gh = g3 - g1;
    G.cb0 = gcx - 2.5f * gw; G.cb1 = gcy - 2.5f * gh;
    G.cb2 = gcx + 2.5f * gw; G.cb3 = gcy + 2.5f * gh;
    G.G0 = g0 / fw; G.G1 = g1 / fh; G.G2 = g2 / fw; G.G3 = g3 / fh;
}

__device__ __forceinline__ void cost_iou(float p0, float p1, float p2, float p3,
        const GtConst& G, float clsv, int validi, float fw, float fh,
        float& cc_out, float& iou_out) {
#pragma clang fp contract(off)
    float area_p = (p2 - p0) * (p3 - p1);
    float wx = fminf(p2, G.g2) - fmaxf(p0, G.g0); wx = fmaxf(wx, 0.0f);
    float wy = fminf(p3, G.g3) - fmaxf(p1, G.g1); wy = fmaxf(wy, 0.0f);
    float inter = wx * wy;
    float uni = area_p + G.area_g - inter;
    float iou = inter / fmaxf(uni, 1e-12f);
    float ex = fmaxf(p2, G.g2) - fminf(p0, G.g0); ex = fmaxf(ex, 0.0f);
    float ey = fmaxf(p3, G.g3) - fminf(p1, G.g1); ey = fmaxf(ey, 0.0f);
    float enc = ex * ey;
    float giou = iou - (enc - uni) / fmaxf(enc, 1e-12f);
    float l1 = ((fabsf(p0 / fw - G.G0) + fabsf(p1 / fh - G.G1))
                + fabsf(p2 / fw - G.G2)) + fabsf(p3 / fh - G.G3);
    float cc = clsv + l1 * 5.0f;
    cc = cc + (-giou * 2.0f);
    float pcx = (p0 + p2) * 0.5f, pcy = (p1 + p3) * 0.5f;
    bool inb = (pcx > G.g0 && pcx < G.g2 && pcy > G.g1 && pcy < G.g3);
    bool inc = (pcx > G.cb0 && pcx < G.cb2 && pcy > G.cb1 && pcy < G.cb3);
    cc = cc + ((inb && inc) ? 0.0f : 100.0f);
    cc = cc + (validi ? 0.0f : 10000.0f);
    cc_out = cc; iou_out = iou;
}

// ---------------------------------------------------------------------------
// Init: zero per-row/col state; rowfirst=INT_MAX; scalars=0.
// ---------------------------------------------------------------------------
__global__ __launch_bounds__(256) void k_init(int* rowcnt, int* rowfirst,
        int* infcnt, int* prior, int* priorcol, int* colsum, int* scal)
{
    int i = blockIdx.x * 256 + threadIdx.x;
    if (i < NP) {
        rowcnt[i] = 0; rowfirst[i] = 0x7fffffff; infcnt[i] = 0;
        prior[i] = 0; priorcol[i] = 0;
    }
    if (i < NG) colsum[i] = 0;
    if (i < 16) scal[i] = 0;
}

// ---------------------------------------------------------------------------
// cls table (column-major [NC][NP]) + per-pred validity.
// ---------------------------------------------------------------------------
__global__ __launch_bounds__(256) void k_clsvalid(const float* __restrict__ logits,
        const float* __restrict__ pb, const float* __restrict__ gb,
        float* __restrict__ clsval, int* __restrict__ valid)
{
    __shared__ float sgb[NG * 4];
    int b = blockIdx.x;
    const int CLS_BLOCKS = (NC * NP) / 256;   // 3125
    if (b < CLS_BLOCKS) {
        int tid = b * 256 + threadIdx.x;      // tid = c*NP + i
        int c = tid / NP;
        int i = tid - c * NP;
        float x = logits[i * NC + c];
        float p = 1.0f / (1.0f + expf(-x));
        float neg = -log1pf(-(p - 1e-12f)) * 0.75f * (p * p);
        float om = 1.0f - p;
        float pos = -logf(p + 1e-12f) * 0.25f * (om * om);
        clsval[tid] = (pos - neg) * 2.0f;     // * CLS_W
    } else {
        for (int t = threadIdx.x; t < NG * 4; t += 256) sgb[t] = gb[t];
        __syncthreads();
        int i = (b - CLS_BLOCKS) * 256 + threadIdx.x;
        if (i < NP) {
            float p0 = pb[i*4+0], p1 = pb[i*4+1], p2 = pb[i*4+2], p3 = pb[i*4+3];
            float pcx = (p0 + p2) * 0.5f, pcy = (p1 + p3) * 0.5f;
            int vb = 0, vc = 0;
            for (int j = 0; j < NG; j++) {
                float g0 = sgb[j*4+0], g1 = sgb[j*4+1], g2 = sgb[j*4+2], g3 = sgb[j*4+3];
                vb |= (pcx > g0 && pcx < g2 && pcy > g1 && pcy < g3) ? 1 : 0;
                float gcx = (g0 + g2) * 0.5f, gcy = (g1 + g3) * 0.5f;
                float gw = g2 - g0, gh = g3 - g1;
                vc |= (pcx > gcx - 2.5f * gw && pcx < gcx + 2.5f * gw &&
                       pcy > gcy - 2.5f * gh && pcy < gcy + 2.5f * gh) ? 1 : 0;
                if (vb & vc) break;
            }
            valid[i] = vb | vc;
        }
    }
}

// ---------------------------------------------------------------------------
// Per-gt column: stream cost (no store), top-5 min-cost (lex) + top-5 max-iou,
// dynamic_k, record picks + initial row assignments.
// ---------------------------------------------------------------------------
__global__ __launch_bounds__(256) void k_cost(
        const float* __restrict__ pb, const float* __restrict__ gb,
        const int* __restrict__ glab, const float* __restrict__ clsval,
        const int* __restrict__ valid, const int* __restrict__ imgw,
        const int* __restrict__ imgh, int* __restrict__ rowcnt,
        int* __restrict__ rowfirst, int* __restrict__ picks,
        int* __restrict__ dkarr)
{
    __shared__ float s_cv[256 * 6];
    __shared__ int   s_ci[256 * 6];
    __shared__ float s_iv[256 * 6];

    int j = blockIdx.x;
    float fw = (float)imgw[0], fh = (float)imgh[0];
    GtConst G; make_gt(((const float4*)gb)[j], fw, fh, G);
    int lbl = glab[j];
    const float* clscol = clsval + (size_t)lbl * NP;
    const float4* pb4 = (const float4*)pb;

    float cv[5]; int ci[5]; float iv[5];
#pragma unroll
    for (int t = 0; t < 5; t++) { cv[t] = FLT_MAX; ci[t] = 0x7fffffff; iv[t] = -1.0f; }

    for (int i = threadIdx.x; i < NP; i += 256) {
        float4 p = pb4[i];
        float cc, iou;
        cost_iou(p.x, p.y, p.z, p.w, G, clscol[i], valid[i], fw, fh, cc, iou);

        if (lexless(cc, i, cv[4], ci[4])) {
            cv[4] = cc; ci[4] = i;
#pragma unroll
            for (int t = 4; t > 0; t--) {
                if (lexless(cv[t], ci[t], cv[t-1], ci[t-1])) {
                    float tv = cv[t]; cv[t] = cv[t-1]; cv[t-1] = tv;
                    int tx = ci[t]; ci[t] = ci[t-1]; ci[t-1] = tx;
                }
            }
        }
        if (iou > iv[4]) {
            iv[4] = iou;
#pragma unroll
            for (int t = 4; t > 0; t--) {
                if (iv[t] > iv[t-1]) { float tv = iv[t]; iv[t] = iv[t-1]; iv[t-1] = tv; }
            }
        }
    }

    int base = threadIdx.x * 6;
#pragma unroll
    for (int t = 0; t < 5; t++) { s_cv[base+t] = cv[t]; s_ci[base+t] = ci[t]; s_iv[base+t] = iv[t]; }
    s_cv[base+5] = FLT_MAX; s_ci[base+5] = 0x7fffffff; s_iv[base+5] = -2.0f;
    __syncthreads();

    for (int w = 128; w > 0; w >>= 1) {
        if (threadIdx.x < (unsigned)w) {
            int a = threadIdx.x * 6, bb = (threadIdx.x + w) * 6;
            float ov[5]; int oi[5]; float og[5];
            int pa = a, pbp = bb;
#pragma unroll
            for (int t = 0; t < 5; t++) {
                float A = s_cv[pa], B = s_cv[pbp];
                int Ai = s_ci[pa], Bi = s_ci[pbp];
                bool tA = (A < B) || (A == B && Ai <= Bi);
                if (tA) { ov[t] = A; oi[t] = Ai; pa++; } else { ov[t] = B; oi[t] = Bi; pbp++; }
            }
            int qa = a, qb = bb;
#pragma unroll
            for (int t = 0; t < 5; t++) {
                float A = s_iv[qa], B = s_iv[qb];
                if (A >= B) { og[t] = A; qa++; } else { og[t] = B; qb++; }
            }
#pragma unroll
            for (int t = 0; t < 5; t++) { s_cv[a+t] = ov[t]; s_ci[a+t] = oi[t]; s_iv[a+t] = og[t]; }
        }
        __syncthreads();
    }

    if (threadIdx.x == 0) {
        float s = (((s_iv[0] + s_iv[1]) + s_iv[2]) + s_iv[3]) + s_iv[4];
        int dk = (int)s;                 // astype(int32): truncation
        if (dk < 1) dk = 1;
        dkarr[j] = dk;
        for (int t = 0; t < dk; t++) {
            int r = s_ci[t];
            picks[j * 5 + t] = r;
            atomicAdd(&rowcnt[r], 1);
            atomicMin(&rowfirst[r], j);
        }
    }
}

// ---------------------------------------------------------------------------
// Prior scan: rows with >1 initial assignment -> prior list.
// ---------------------------------------------------------------------------
__global__ __launch_bounds__(256) void k_pscan(const int* __restrict__ rowcnt,
        int* __restrict__ prior, int* __restrict__ plist, int* __restrict__ scal)
{
    int i = blockIdx.x * 256 + threadIdx.x;
    if (i >= NP) return;
    if (rowcnt[i] > 1) {
        prior[i] = 1;
        int idx = atomicAdd(&scal[S_NPRI], 1);
        plist[idx] = i;
    }
}

// ---------------------------------------------------------------------------
// Prior fix: block per prior row; cooperative argmin over the row's
// (recomputed, uninflated) cost -> priorcol; contribute to colsum.
// ---------------------------------------------------------------------------
__global__ __launch_bounds__(256) void k_pfix(const float* __restrict__ pb,
        const float* __restrict__ gb, const int* __restrict__ glab,
        const float* __restrict__ clsval, const int* __restrict__ valid,
        const int* __restrict__ imgw, const int* __restrict__ imgh,
        const int* __restrict__ plist, int* __restrict__ priorcol,
        int* __restrict__ colsum, const int* __restrict__ scal)
{
    if ((int)blockIdx.x >= scal[S_NPRI]) return;
    int row = plist[blockIdx.x];
    float fw = (float)imgw[0], fh = (float)imgh[0];
    float4 p = ((const float4*)pb)[row];
    int vld = valid[row];
    const float4* gb4 = (const float4*)gb;

    __shared__ float rv[256]; __shared__ int ri[256];
    float best = FLT_MAX; int bj = 0x7fffffff;
    for (int j = threadIdx.x; j < NG; j += 256) {
        GtConst G; make_gt(gb4[j], fw, fh, G);
        float cc, iou;
        cost_iou(p.x, p.y, p.z, p.w, G, clsval[(size_t)glab[j] * NP + row], vld, fw, fh, cc, iou);
        if (lexless(cc, j, best, bj)) { best = cc; bj = j; }
    }
    rv[threadIdx.x] = best; ri[threadIdx.x] = bj; __syncthreads();
    for (int w = 128; w > 0; w >>= 1) {
        if (threadIdx.x < (unsigned)w) {
            float ov = rv[threadIdx.x + w]; int oi = ri[threadIdx.x + w];
            if (lexless(ov, oi, rv[threadIdx.x], ri[threadIdx.x])) {
                rv[threadIdx.x] = ov; ri[threadIdx.x] = oi;
            }
        }
        __syncthreads();
    }
    if (threadIdx.x == 0) {
        priorcol[row] = ri[0];
        atomicAdd(&colsum[ri[0]], 1);
    }
}

// ---------------------------------------------------------------------------
// Surviving initial picks -> colsum (rows that kept their single assignment).
// ---------------------------------------------------------------------------
__global__ __launch_bounds__(256) void k_surv(const int* __restrict__ rowcnt,
        const int* __restrict__ picks, const int* __restrict__ dkarr,
        int* __restrict__ colsum)
{
    int j = blockIdx.x * 256 + threadIdx.x;
    if (j >= NG) return;
    int c = 0;
    int dk = dkarr[j];
    for (int t = 0; t < dk; t++) if (rowcnt[picks[j * 5 + t]] == 1) c++;
    colsum[j] += c;
}

// ---------------------------------------------------------------------------
// iterA: single block. t==0: numUnmatched from colsum scan. Set body flag.
// If active: inflate matched rows (infcnt++).
// ---------------------------------------------------------------------------
__global__ __launch_bounds__(1024) void k_iterA(const int* __restrict__ colsum,
        const int* __restrict__ rowcnt, int* __restrict__ infcnt,
        int* __restrict__ scal, int t)
{
    __shared__ int red[1024];
    __shared__ int sflag;
    if (t > 0 && scal[2 * (t - 1)] == 0) return;   // flags pre-zeroed
    if (t == 0) {
        int c = (threadIdx.x < NG && colsum[threadIdx.x] == 0) ? 1 : 0;
        red[threadIdx.x] = c; __syncthreads();
        for (int w = 512; w > 0; w >>= 1) {
            if (threadIdx.x < (unsigned)w) red[threadIdx.x] += red[threadIdx.x + w];
            __syncthreads();
        }
        if (threadIdx.x == 0) scal[S_NUNM] = red[0];
        __syncthreads();
    }
    if (threadIdx.x == 0) { sflag = (scal[S_NUNM] > 0) ? 1 : 0; scal[2 * t] = sflag; }
    __syncthreads();
    if (!sflag) return;
    for (int i = threadIdx.x; i < NP; i += 1024)
        if (rowcnt[i] > 0) infcnt[i]++;
}

// ---------------------------------------------------------------------------
// iterB: block per column; unmatched columns pick argmin_i of virtually-
// inflated recomputed cost. Maintain rowcnt/rowfirst/colsum/numUnmatched;
// collision -> persistent anymulti.
// ---------------------------------------------------------------------------
__global__ __launch_bounds__(256) void k_iterB(const float* __restrict__ pb,
        const float* __restrict__ gb, const int* __restrict__ glab,
        const float* __restrict__ clsval, const int* __restrict__ valid,
        const int* __restrict__ imgw, const int* __restrict__ imgh,
        const int* __restrict__ infcnt, int* __restrict__ rowcnt,
        int* __restrict__ rowfirst, int* __restrict__ colsum,
        int* __restrict__ scal, int t)
{
    if (scal[2 * t] == 0) return;
    int j = blockIdx.x;
    if (colsum[j] != 0) return;

    float fw = (float)imgw[0], fh = (float)imgh[0];
    GtConst G; make_gt(((const float4*)gb)[j], fw, fh, G);
    const float* clscol = clsval + (size_t)glab[j] * NP;
    const float4* pb4 = (const float4*)pb;

    __shared__ float rv[256]; __shared__ int ri[256];
    float best = FLT_MAX; int bi = 0x7fffffff;
    for (int i = threadIdx.x; i < NP; i += 256) {
        float4 p = pb4[i];
        float cc, iou;
        cost_iou(p.x, p.y, p.z, p.w, G, clscol[i], valid[i], fw, fh, cc, iou);
        float val = inflate(cc, infcnt[i]);
        if (lexless(val, i, best, bi)) { best = val; bi = i; }
    }
    rv[threadIdx.x] = best; ri[threadIdx.x] = bi; __syncthreads();
    for (int w = 128; w > 0; w >>= 1) {
        if (threadIdx.x < (unsigned)w) {
            float ov = rv[threadIdx.x + w]; int oi = ri[threadIdx.x + w];
            if (lexless(ov, oi, rv[threadIdx.x], ri[threadIdx.x])) {
                rv[threadIdx.x] = ov; ri[threadIdx.x] = oi;
            }
        }
        __syncthreads();
    }
    if (threadIdx.x == 0) {
        int pos = ri[0];
        colsum[j] = 1;
        atomicSub(&scal[S_NUNM], 1);
        int old = atomicAdd(&rowcnt[pos], 1);
        if (old >= 1) scal[S_MULTI] = 1;   // persistent; racing writes store same value
        atomicMin(&rowfirst[pos], j);
    }
}

// ---------------------------------------------------------------------------
// iterC (m_fix): when body active && anymulti, every prior row re-argmins its
// (inflated, row-uniform) cost; move its column if changed.
// ---------------------------------------------------------------------------
__global__ __launch_bounds__(256) void k_iterC(const float* __restrict__ pb,
        const float* __restrict__ gb, const int* __restrict__ glab,
        const float* __restrict__ clsval, const int* __restrict__ valid,
        const int* __restrict__ imgw, const int* __restrict__ imgh,
        const int* __restrict__ plist, const int* __restrict__ infcnt,
        int* __restrict__ priorcol, int* __restrict__ colsum,
        int* __restrict__ scal, int t)
{
    if (scal[2 * t] == 0 || scal[S_MULTI] == 0) return;
    if ((int)blockIdx.x >= scal[S_NPRI]) return;
    int row = plist[blockIdx.x];
    int k = infcnt[row];
    float fw = (float)imgw[0], fh = (float)imgh[0];
    float4 p = ((const float4*)pb)[row];
    int vld = valid[row];
    const float4* gb4 = (const float4*)gb;

    __shared__ float rv[256]; __shared__ int ri[256];
    float best = FLT_MAX; int bj = 0x7fffffff;
    for (int j = threadIdx.x; j < NG; j += 256) {
        GtConst G; make_gt(gb4[j], fw, fh, G);
        float cc, iou;
        cost_iou(p.x, p.y, p.z, p.w, G, clsval[(size_t)glab[j] * NP + row], vld, fw, fh, cc, iou);
        float val = inflate(cc, k);
        if (lexless(val, j, best, bj)) { best = val; bj = j; }
    }
    rv[threadIdx.x] = best; ri[threadIdx.x] = bj; __syncthreads();
    for (int w = 128; w > 0; w >>= 1) {
        if (threadIdx.x < (unsigned)w) {
            float ov = rv[threadIdx.x + w]; int oi = ri[threadIdx.x + w];
            if (lexless(ov, oi, rv[threadIdx.x], ri[threadIdx.x])) {
                rv[threadIdx.x] = ov; ri[threadIdx.x] = oi;
            }
        }
        __syncthreads();
    }
    if (threadIdx.x == 0) {
        int nb = ri[0];
        int oldc = priorcol[row];
        if (nb != oldc) {
            int oa = atomicSub(&colsum[oldc], 1);
            if (oa == 1) atomicAdd(&scal[S_NUNM], 1);
            int ob = atomicAdd(&colsum[nb], 1);
            if (ob == 0) atomicSub(&scal[S_NUNM], 1);
            priorcol[row] = nb;
        }
    }
}

// ---------------------------------------------------------------------------
// Final: fg = rowcnt>0; matched col = priorcol (prior) else rowfirst; int32 out.
// ---------------------------------------------------------------------------
__global__ __launch_bounds__(256) void k_final(const int* __restrict__ rowcnt,
        const int* __restrict__ prior, const int* __restrict__ priorcol,
        const int* __restrict__ rowfirst, int* __restrict__ out)
{
    int i = blockIdx.x * 256 + threadIdx.x;
    if (i >= NP) return;
    int fg = rowcnt[i] > 0;
    out[i] = fg ? 1 : 0;
    out[NP + i] = fg ? (prior[i] ? priorcol[i] : rowfirst[i]) : 0;
}

extern "C" void kernel_launch(void* const* d_in, const int* in_sizes, int n_in,
                              void* d_out, int out_size, void* d_ws, size_t ws_size,
                              hipStream_t stream)
{
    (void)in_sizes; (void)n_in; (void)out_size; (void)ws_size;
    const float* logits = (const float*)d_in[0];
    const float* pboxes = (const float*)d_in[1];
    const float* gboxes = (const float*)d_in[2];
    const int*   glab   = (const int*)d_in[3];
    const int*   imgh   = (const int*)d_in[4];
    const int*   imgw   = (const int*)d_in[5];
    int* out = (int*)d_out;

    char* w = (char*)d_ws;
    float* clsval  = (float*)(w);                    // 3,200,000
    int* valid     = (int*)(w + 3200000);            // 40,000
    int* rowcnt    = (int*)(w + 3240000);            // 40,000
    int* rowfirst  = (int*)(w + 3280000);            // 40,000
    int* infcnt    = (int*)(w + 3320000);            // 40,000
    int* prior     = (int*)(w + 3360000);            // 40,000
    int* priorcol  = (int*)(w + 3400000);            // 40,000
    int* plist     = (int*)(w + 3440000);            // 40,000
    int* picks     = (int*)(w + 3480000);            // 20,000
    int* dkarr     = (int*)(w + 3500000);            // 4,000
    int* colsum    = (int*)(w + 3504000);            // 4,000
    int* scal      = (int*)(w + 3508000);            // 64

    hipLaunchKernelGGL(k_init, dim3(40), dim3(256), 0, stream,
                       rowcnt, rowfirst, infcnt, prior, priorcol, colsum, scal);
    hipLaunchKernelGGL(k_clsvalid, dim3(3165), dim3(256), 0, stream,
                       logits, pboxes, gboxes, clsval, valid);
    hipLaunchKernelGGL(k_cost, dim3(NG), dim3(256), 0, stream,
                       pboxes, gboxes, glab, clsval, valid, imgw, imgh,
                       rowcnt, rowfirst, picks, dkarr);
    hipLaunchKernelGGL(k_pscan, dim3(40), dim3(256), 0, stream,
                       rowcnt, prior, plist, scal);
    hipLaunchKernelGGL(k_pfix, dim3(2500), dim3(256), 0, stream,
                       pboxes, gboxes, glab, clsval, valid, imgw, imgh,
                       plist, priorcol, colsum, scal);
    hipLaunchKernelGGL(k_surv, dim3(4), dim3(256), 0, stream,
                       rowcnt, picks, dkarr, colsum);
    for (int t = 0; t < LMAX; t++) {
        hipLaunchKernelGGL(k_iterA, dim3(1), dim3(1024), 0, stream,
                           colsum, rowcnt, infcnt, scal, t);
        hipLaunchKernelGGL(k_iterB, dim3(NG), dim3(256), 0, stream,
                           pboxes, gboxes, glab, clsval, valid, imgw, imgh,
                           infcnt, rowcnt, rowfirst, colsum, scal, t);
        hipLaunchKernelGGL(k_iterC, dim3(2500), dim3(256), 0, stream,
                           pboxes, gboxes, glab, clsval, valid, imgw, imgh,
                           plist, infcnt, priorcol, colsum, scal, t);
    }
    hipLaunchKernelGGL(k_final, dim3(40), dim3(256), 0, stream,
                       rowcnt, prior, priorcol, rowfirst, out);
}

// Round 4
// 243.638 us; speedup vs baseline: 3.4199x; 1.9041x over previous
//
#include <hip/hip_runtime.h>
#include <cfloat>
#include <cmath>

#define NP 10000
#define NG 1000
#define NC 80
#define LMAX 6

// scal[] layout: [0..2*LMAX-1] flags (2t = body-active), [12] anymulti
// (persistent), [13] numUnmatched, [14] nprior
#define S_MULTI 12
#define S_NUNM  13
#define S_NPRI  14

__device__ __forceinline__ bool lexless(float av, int ai, float bv, int bi) {
    return (av < bv) || (av == bv && ai < bi);
}

// Exact sequential +1e5 inflation (reference adds 1e5 once per loop iteration).
__device__ __forceinline__ float inflate(float c, int k) {
    for (int q = 0; q < k; q++) c += 100000.0f;
    return c;
}

struct GtConst {
    float g0, g1, g2, g3, area_g;
    float cb0, cb1, cb2, cb3;
    float G0, G1, G2, G3;
};

// All cost-affecting arithmetic with contraction OFF so every kernel that
// recomputes cost(i,j) gets bit-identical values.
__device__ __forceinline__ void make_gt(const float4 gv, float fw, float fh, GtConst& G) {
#pragma clang fp contract(off)
    float g0 = gv.x, g1 = gv.y, g2 = gv.z, g3 = gv.w;
    G.g0 = g0; G.g1 = g1; G.g2 = g2; G.g3 = g3;
    G.area_g = (g2 - g0) * (g3 - g1);
    float gcx = (g0 + g2) * 0.5f, gcy = (g1 + g3) * 0.5f;
    float gw = g2 - g0, gh = g3 - g1;
    G.cb0 = gcx - 2.5f * gw; G.cb1 = gcy - 2.5f * gh;
    G.cb2 = gcx + 2.5f * gw; G.cb3 = gcy + 2.5f * gh;
    G.G0 = g0 / fw; G.G1 = g1 / fh; G.G2 = g2 / fw; G.G3 = g3 / fh;
}

__device__ __forceinline__ void cost_iou(float p0, float p1, float p2, float p3,
        const GtConst& G, float clsv, int validi, float fw, float fh,
        float& cc_out, float& iou_out) {
#pragma clang fp contract(off)
    float area_p = (p2 - p0) * (p3 - p1);
    float wx = fminf(p2, G.g2) - fmaxf(p0, G.g0); wx = fmaxf(wx, 0.0f);
    float wy = fminf(p3, G.g3) - fmaxf(p1, G.g1); wy = fmaxf(wy, 0.0f);
    float inter = wx * wy;
    float uni = area_p + G.area_g - inter;
    float iou = inter / fmaxf(uni, 1e-12f);
    float ex = fmaxf(p2, G.g2) - fminf(p0, G.g0); ex = fmaxf(ex, 0.0f);
    float ey = fmaxf(p3, G.g3) - fminf(p1, G.g1); ey = fmaxf(ey, 0.0f);
    float enc = ex * ey;
    float giou = iou - (enc - uni) / fmaxf(enc, 1e-12f);
    float l1 = ((fabsf(p0 / fw - G.G0) + fabsf(p1 / fh - G.G1))
                + fabsf(p2 / fw - G.G2)) + fabsf(p3 / fh - G.G3);
    float cc = clsv + l1 * 5.0f;
    cc = cc + (-giou * 2.0f);
    float pcx = (p0 + p2) * 0.5f, pcy = (p1 + p3) * 0.5f;
    bool inb = (pcx > G.g0 && pcx < G.g2 && pcy > G.g1 && pcy < G.g3);
    bool inc = (pcx > G.cb0 && pcx < G.cb2 && pcy > G.cb1 && pcy < G.cb3);
    cc = cc + ((inb && inc) ? 0.0f : 100.0f);
    cc = cc + (validi ? 0.0f : 10000.0f);
    cc_out = cc; iou_out = iou;
}

// ---------------------------------------------------------------------------
// Init: zero per-row/col state; rowfirst=INT_MAX; scalars=0.
// ---------------------------------------------------------------------------
__global__ __launch_bounds__(256) void k_init(int* rowcnt, int* rowfirst,
        int* infcnt, int* prior, int* priorcol, int* colsum, int* scal)
{
    int i = blockIdx.x * 256 + threadIdx.x;
    if (i < NP) {
        rowcnt[i] = 0; rowfirst[i] = 0x7fffffff; infcnt[i] = 0;
        prior[i] = 0; priorcol[i] = 0;
    }
    if (i < NG) colsum[i] = 0;
    if (i < 16) scal[i] = 0;
}

// ---------------------------------------------------------------------------
// cls table (column-major [NC][NP]). 64 preds/block; coalesced logits load ->
// LDS transpose (pad 80->81: bank=(17*di+c)%32, conflict-free) -> coalesced
// column-major store.
// ---------------------------------------------------------------------------
#define CLS_TI 64
__global__ __launch_bounds__(256) void k_cls(const float* __restrict__ logits,
        float* __restrict__ clsval)
{
    __shared__ float sl[CLS_TI * (NC + 1)];
    int i0 = blockIdx.x * CLS_TI;
    bool full = (i0 + CLS_TI) <= NP;
    if (full) {
        const float* src = logits + (size_t)i0 * NC;
        for (int e = threadIdx.x; e < CLS_TI * NC; e += 256) {
            int di = e / NC, c = e - di * NC;
            sl[di * (NC + 1) + c] = src[e];
        }
    } else {
        for (int e = threadIdx.x; e < CLS_TI * NC; e += 256) {
            int di = e / NC, c = e - di * NC;
            int i = i0 + di;
            sl[di * (NC + 1) + c] = (i < NP) ? logits[(size_t)i * NC + c] : 0.0f;
        }
    }
    __syncthreads();
    for (int e = threadIdx.x; e < CLS_TI * NC; e += 256) {
        int c = e >> 6, di = e & 63;
        int i = i0 + di;
        if (i >= NP) continue;
        float x = sl[di * (NC + 1) + c];
        float p = 1.0f / (1.0f + expf(-x));
        float neg = -log1pf(-(p - 1e-12f)) * 0.75f * (p * p);
        float om = 1.0f - p;
        float pos = -logf(p + 1e-12f) * 0.25f * (om * om);
        clsval[(size_t)c * NP + i] = (pos - neg) * 2.0f;   // * CLS_W
    }
}

// ---------------------------------------------------------------------------
// Validity: wave per pred; 64 lanes stride the 1000 gts; __any reduce.
// valid = any_j(in_boxes) | any_j(in_centers)
// ---------------------------------------------------------------------------
__global__ __launch_bounds__(256) void k_valid(const float* __restrict__ pb,
        const float* __restrict__ gb, int* __restrict__ valid)
{
#pragma clang fp contract(off)
    int wave = threadIdx.x >> 6;
    int lane = threadIdx.x & 63;
    int i = blockIdx.x * 4 + wave;
    if (i >= NP) return;
    float4 p = ((const float4*)pb)[i];
    float pcx = (p.x + p.z) * 0.5f, pcy = (p.y + p.w) * 0.5f;
    int vb = 0, vc = 0;
    const float4* gb4 = (const float4*)gb;
    for (int j = lane; j < NG; j += 64) {
        float4 g = gb4[j];
        vb |= (pcx > g.x && pcx < g.z && pcy > g.y && pcy < g.w) ? 1 : 0;
        float gcx = (g.x + g.z) * 0.5f, gcy = (g.y + g.w) * 0.5f;
        float gw = g.z - g.x, gh = g.w - g.y;
        vc |= (pcx > gcx - 2.5f * gw && pcx < gcx + 2.5f * gw &&
               pcy > gcy - 2.5f * gh && pcy < gcy + 2.5f * gh) ? 1 : 0;
    }
    int any = (__any(vb) ? 1 : 0) | (__any(vc) ? 1 : 0);
    if (lane == 0) valid[i] = any;
}

// ---------------------------------------------------------------------------
// Per-gt column: stream cost (no store), top-5 min-cost (lex) + top-5 max-iou,
// dynamic_k, record picks + initial row assignments.
// ---------------------------------------------------------------------------
__global__ __launch_bounds__(256) void k_cost(
        const float* __restrict__ pb, const float* __restrict__ gb,
        const int* __restrict__ glab, const float* __restrict__ clsval,
        const int* __restrict__ valid, const int* __restrict__ imgw,
        const int* __restrict__ imgh, int* __restrict__ rowcnt,
        int* __restrict__ rowfirst, int* __restrict__ picks,
        int* __restrict__ dkarr)
{
    __shared__ float s_cv[256 * 6];
    __shared__ int   s_ci[256 * 6];
    __shared__ float s_iv[256 * 6];

    int j = blockIdx.x;
    float fw = (float)imgw[0], fh = (float)imgh[0];
    GtConst G; make_gt(((const float4*)gb)[j], fw, fh, G);
    int lbl = glab[j];
    const float* clscol = clsval + (size_t)lbl * NP;
    const float4* pb4 = (const float4*)pb;

    float cv[5]; int ci[5]; float iv[5];
#pragma unroll
    for (int t = 0; t < 5; t++) { cv[t] = FLT_MAX; ci[t] = 0x7fffffff; iv[t] = -1.0f; }

    for (int i = threadIdx.x; i < NP; i += 256) {
        float4 p = pb4[i];
        float cc, iou;
        cost_iou(p.x, p.y, p.z, p.w, G, clscol[i], valid[i], fw, fh, cc, iou);

        if (lexless(cc, i, cv[4], ci[4])) {
            cv[4] = cc; ci[4] = i;
#pragma unroll
            for (int t = 4; t > 0; t--) {
                if (lexless(cv[t], ci[t], cv[t-1], ci[t-1])) {
                    float tv = cv[t]; cv[t] = cv[t-1]; cv[t-1] = tv;
                    int tx = ci[t]; ci[t] = ci[t-1]; ci[t-1] = tx;
                }
            }
        }
        if (iou > iv[4]) {
            iv[4] = iou;
#pragma unroll
            for (int t = 4; t > 0; t--) {
                if (iv[t] > iv[t-1]) { float tv = iv[t]; iv[t] = iv[t-1]; iv[t-1] = tv; }
            }
        }
    }

    int base = threadIdx.x * 6;
#pragma unroll
    for (int t = 0; t < 5; t++) { s_cv[base+t] = cv[t]; s_ci[base+t] = ci[t]; s_iv[base+t] = iv[t]; }
    s_cv[base+5] = FLT_MAX; s_ci[base+5] = 0x7fffffff; s_iv[base+5] = -2.0f;
    __syncthreads();

    for (int w = 128; w > 0; w >>= 1) {
        if (threadIdx.x < (unsigned)w) {
            int a = threadIdx.x * 6, bb = (threadIdx.x + w) * 6;
            float ov[5]; int oi[5]; float og[5];
            int pa = a, pbp = bb;
#pragma unroll
            for (int t = 0; t < 5; t++) {
                float A = s_cv[pa], B = s_cv[pbp];
                int Ai = s_ci[pa], Bi = s_ci[pbp];
                bool tA = (A < B) || (A == B && Ai <= Bi);
                if (tA) { ov[t] = A; oi[t] = Ai; pa++; } else { ov[t] = B; oi[t] = Bi; pbp++; }
            }
            int qa = a, qb = bb;
#pragma unroll
            for (int t = 0; t < 5; t++) {
                float A = s_iv[qa], B = s_iv[qb];
                if (A >= B) { og[t] = A; qa++; } else { og[t] = B; qb++; }
            }
#pragma unroll
            for (int t = 0; t < 5; t++) { s_cv[a+t] = ov[t]; s_ci[a+t] = oi[t]; s_iv[a+t] = og[t]; }
        }
        __syncthreads();
    }

    if (threadIdx.x == 0) {
        float s = (((s_iv[0] + s_iv[1]) + s_iv[2]) + s_iv[3]) + s_iv[4];
        int dk = (int)s;                 // astype(int32): truncation
        if (dk < 1) dk = 1;
        dkarr[j] = dk;
        for (int t = 0; t < dk; t++) {
            int r = s_ci[t];
            picks[j * 5 + t] = r;
            atomicAdd(&rowcnt[r], 1);
            atomicMin(&rowfirst[r], j);
        }
    }
}

// ---------------------------------------------------------------------------
// Prior scan: rows with >1 initial assignment -> prior list.
// ---------------------------------------------------------------------------
__global__ __launch_bounds__(256) void k_pscan(const int* __restrict__ rowcnt,
        int* __restrict__ prior, int* __restrict__ plist, int* __restrict__ scal)
{
    int i = blockIdx.x * 256 + threadIdx.x;
    if (i >= NP) return;
    if (rowcnt[i] > 1) {
        prior[i] = 1;
        int idx = atomicAdd(&scal[S_NPRI], 1);
        plist[idx] = i;
    }
}

// ---------------------------------------------------------------------------
// Prior fix: block per prior row; cooperative argmin over the row's
// (recomputed, uninflated) cost -> priorcol; contribute to colsum.
// ---------------------------------------------------------------------------
__global__ __launch_bounds__(256) void k_pfix(const float* __restrict__ pb,
        const float* __restrict__ gb, const int* __restrict__ glab,
        const float* __restrict__ clsval, const int* __restrict__ valid,
        const int* __restrict__ imgw, const int* __restrict__ imgh,
        const int* __restrict__ plist, int* __restrict__ priorcol,
        int* __restrict__ colsum, const int* __restrict__ scal)
{
    if ((int)blockIdx.x >= scal[S_NPRI]) return;
    int row = plist[blockIdx.x];
    float fw = (float)imgw[0], fh = (float)imgh[0];
    float4 p = ((const float4*)pb)[row];
    int vld = valid[row];
    const float4* gb4 = (const float4*)gb;

    __shared__ float rv[256]; __shared__ int ri[256];
    float best = FLT_MAX; int bj = 0x7fffffff;
    for (int j = threadIdx.x; j < NG; j += 256) {
        GtConst G; make_gt(gb4[j], fw, fh, G);
        float cc, iou;
        cost_iou(p.x, p.y, p.z, p.w, G, clsval[(size_t)glab[j] * NP + row], vld, fw, fh, cc, iou);
        if (lexless(cc, j, best, bj)) { best = cc; bj = j; }
    }
    rv[threadIdx.x] = best; ri[threadIdx.x] = bj; __syncthreads();
    for (int w = 128; w > 0; w >>= 1) {
        if (threadIdx.x < (unsigned)w) {
            float ov = rv[threadIdx.x + w]; int oi = ri[threadIdx.x + w];
            if (lexless(ov, oi, rv[threadIdx.x], ri[threadIdx.x])) {
                rv[threadIdx.x] = ov; ri[threadIdx.x] = oi;
            }
        }
        __syncthreads();
    }
    if (threadIdx.x == 0) {
        priorcol[row] = ri[0];
        atomicAdd(&colsum[ri[0]], 1);
    }
}

// ---------------------------------------------------------------------------
// Surviving initial picks -> colsum (rows that kept their single assignment).
// ---------------------------------------------------------------------------
__global__ __launch_bounds__(256) void k_surv(const int* __restrict__ rowcnt,
        const int* __restrict__ picks, const int* __restrict__ dkarr,
        int* __restrict__ colsum)
{
    int j = blockIdx.x * 256 + threadIdx.x;
    if (j >= NG) return;
    int c = 0;
    int dk = dkarr[j];
    for (int t = 0; t < dk; t++) if (rowcnt[picks[j * 5 + t]] == 1) c++;
    colsum[j] += c;
}

// ---------------------------------------------------------------------------
// iterA: single block. t==0: numUnmatched from colsum scan. Set body flag.
// If active: inflate matched rows (infcnt++).
// ---------------------------------------------------------------------------
__global__ __launch_bounds__(1024) void k_iterA(const int* __restrict__ colsum,
        const int* __restrict__ rowcnt, int* __restrict__ infcnt,
        int* __restrict__ scal, int t)
{
    __shared__ int red[1024];
    __shared__ int sflag;
    if (t > 0 && scal[2 * (t - 1)] == 0) return;   // flags pre-zeroed
    if (t == 0) {
        int c = (threadIdx.x < NG && colsum[threadIdx.x] == 0) ? 1 : 0;
        red[threadIdx.x] = c; __syncthreads();
        for (int w = 512; w > 0; w >>= 1) {
            if (threadIdx.x < (unsigned)w) red[threadIdx.x] += red[threadIdx.x + w];
            __syncthreads();
        }
        if (threadIdx.x == 0) scal[S_NUNM] = red[0];
        __syncthreads();
    }
    if (threadIdx.x == 0) { sflag = (scal[S_NUNM] > 0) ? 1 : 0; scal[2 * t] = sflag; }
    __syncthreads();
    if (!sflag) return;
    for (int i = threadIdx.x; i < NP; i += 1024)
        if (rowcnt[i] > 0) infcnt[i]++;
}

// ---------------------------------------------------------------------------
// iterB: block per column; unmatched columns pick argmin_i of virtually-
// inflated recomputed cost. Maintain rowcnt/rowfirst/colsum/numUnmatched;
// collision -> persistent anymulti.
// ---------------------------------------------------------------------------
__global__ __launch_bounds__(256) void k_iterB(const float* __restrict__ pb,
        const float* __restrict__ gb, const int* __restrict__ glab,
        const float* __restrict__ clsval, const int* __restrict__ valid,
        const int* __restrict__ imgw, const int* __restrict__ imgh,
        const int* __restrict__ infcnt, int* __restrict__ rowcnt,
        int* __restrict__ rowfirst, int* __restrict__ colsum,
        int* __restrict__ scal, int t)
{
    if (scal[2 * t] == 0) return;
    int j = blockIdx.x;
    if (colsum[j] != 0) return;

    float fw = (float)imgw[0], fh = (float)imgh[0];
    GtConst G; make_gt(((const float4*)gb)[j], fw, fh, G);
    const float* clscol = clsval + (size_t)glab[j] * NP;
    const float4* pb4 = (const float4*)pb;

    __shared__ float rv[256]; __shared__ int ri[256];
    float best = FLT_MAX; int bi = 0x7fffffff;
    for (int i = threadIdx.x; i < NP; i += 256) {
        float4 p = pb4[i];
        float cc, iou;
        cost_iou(p.x, p.y, p.z, p.w, G, clscol[i], valid[i], fw, fh, cc, iou);
        float val = inflate(cc, infcnt[i]);
        if (lexless(val, i, best, bi)) { best = val; bi = i; }
    }
    rv[threadIdx.x] = best; ri[threadIdx.x] = bi; __syncthreads();
    for (int w = 128; w > 0; w >>= 1) {
        if (threadIdx.x < (unsigned)w) {
            float ov = rv[threadIdx.x + w]; int oi = ri[threadIdx.x + w];
            if (lexless(ov, oi, rv[threadIdx.x], ri[threadIdx.x])) {
                rv[threadIdx.x] = ov; ri[threadIdx.x] = oi;
            }
        }
        __syncthreads();
    }
    if (threadIdx.x == 0) {
        int pos = ri[0];
        colsum[j] = 1;
        atomicSub(&scal[S_NUNM], 1);
        int old = atomicAdd(&rowcnt[pos], 1);
        if (old >= 1) scal[S_MULTI] = 1;   // persistent; racing writes store same value
        atomicMin(&rowfirst[pos], j);
    }
}

// ---------------------------------------------------------------------------
// iterC (m_fix): when body active && anymulti, every prior row re-argmins its
// (inflated, row-uniform) cost; move its column if changed.
// ---------------------------------------------------------------------------
__global__ __launch_bounds__(256) void k_iterC(const float* __restrict__ pb,
        const float* __restrict__ gb, const int* __restrict__ glab,
        const float* __restrict__ clsval, const int* __restrict__ valid,
        const int* __restrict__ imgw, const int* __restrict__ imgh,
        const int* __restrict__ plist, const int* __restrict__ infcnt,
        int* __restrict__ priorcol, int* __restrict__ colsum,
        int* __restrict__ scal, int t)
{
    if (scal[2 * t] == 0 || scal[S_MULTI] == 0) return;
    if ((int)blockIdx.x >= scal[S_NPRI]) return;
    int row = plist[blockIdx.x];
    int k = infcnt[row];
    float fw = (float)imgw[0], fh = (float)imgh[0];
    float4 p = ((const float4*)pb)[row];
    int vld = valid[row];
    const float4* gb4 = (const float4*)gb;

    __shared__ float rv[256]; __shared__ int ri[256];
    float best = FLT_MAX; int bj = 0x7fffffff;
    for (int j = threadIdx.x; j < NG; j += 256) {
        GtConst G; make_gt(gb4[j], fw, fh, G);
        float cc, iou;
        cost_iou(p.x, p.y, p.z, p.w, G, clsval[(size_t)glab[j] * NP + row], vld, fw, fh, cc, iou);
        float val = inflate(cc, k);
        if (lexless(val, j, best, bj)) { best = val; bj = j; }
    }
    rv[threadIdx.x] = best; ri[threadIdx.x] = bj; __syncthreads();
    for (int w = 128; w > 0; w >>= 1) {
        if (threadIdx.x < (unsigned)w) {
            float ov = rv[threadIdx.x + w]; int oi = ri[threadIdx.x + w];
            if (lexless(ov, oi, rv[threadIdx.x], ri[threadIdx.x])) {
                rv[threadIdx.x] = ov; ri[threadIdx.x] = oi;
            }
        }
        __syncthreads();
    }
    if (threadIdx.x == 0) {
        int nb = ri[0];
        int oldc = priorcol[row];
        if (nb != oldc) {
            int oa = atomicSub(&colsum[oldc], 1);
            if (oa == 1) atomicAdd(&scal[S_NUNM], 1);
            int ob = atomicAdd(&colsum[nb], 1);
            if (ob == 0) atomicSub(&scal[S_NUNM], 1);
            priorcol[row] = nb;
        }
    }
}

// ---------------------------------------------------------------------------
// Final: fg = rowcnt>0; matched col = priorcol (prior) else rowfirst; int32 out.
// ---------------------------------------------------------------------------
__global__ __launch_bounds__(256) void k_final(const int* __restrict__ rowcnt,
        const int* __restrict__ prior, const int* __restrict__ priorcol,
        const int* __restrict__ rowfirst, int* __restrict__ out)
{
    int i = blockIdx.x * 256 + threadIdx.x;
    if (i >= NP) return;
    int fg = rowcnt[i] > 0;
    out[i] = fg ? 1 : 0;
    out[NP + i] = fg ? (prior[i] ? priorcol[i] : rowfirst[i]) : 0;
}

extern "C" void kernel_launch(void* const* d_in, const int* in_sizes, int n_in,
                              void* d_out, int out_size, void* d_ws, size_t ws_size,
                              hipStream_t stream)
{
    (void)in_sizes; (void)n_in; (void)out_size; (void)ws_size;
    const float* logits = (const float*)d_in[0];
    const float* pboxes = (const float*)d_in[1];
    const float* gboxes = (const float*)d_in[2];
    const int*   glab   = (const int*)d_in[3];
    const int*   imgh   = (const int*)d_in[4];
    const int*   imgw   = (const int*)d_in[5];
    int* out = (int*)d_out;

    char* w = (char*)d_ws;
    float* clsval  = (float*)(w);                    // 3,200,000
    int* valid     = (int*)(w + 3200000);            // 40,000
    int* rowcnt    = (int*)(w + 3240000);            // 40,000
    int* rowfirst  = (int*)(w + 3280000);            // 40,000
    int* infcnt    = (int*)(w + 3320000);            // 40,000
    int* prior     = (int*)(w + 3360000);            // 40,000
    int* priorcol  = (int*)(w + 3400000);            // 40,000
    int* plist     = (int*)(w + 3440000);            // 40,000
    int* picks     = (int*)(w + 3480000);            // 20,000
    int* dkarr     = (int*)(w + 3500000);            // 4,000
    int* colsum    = (int*)(w + 3504000);            // 4,000
    int* scal      = (int*)(w + 3508000);            // 64

    hipLaunchKernelGGL(k_init, dim3(40), dim3(256), 0, stream,
                       rowcnt, rowfirst, infcnt, prior, priorcol, colsum, scal);
    hipLaunchKernelGGL(k_cls, dim3((NP + CLS_TI - 1) / CLS_TI), dim3(256), 0, stream,
                       logits, clsval);
    hipLaunchKernelGGL(k_valid, dim3(2500), dim3(256), 0, stream,
                       pboxes, gboxes, valid);
    hipLaunchKernelGGL(k_cost, dim3(NG), dim3(256), 0, stream,
                       pboxes, gboxes, glab, clsval, valid, imgw, imgh,
                       rowcnt, rowfirst, picks, dkarr);
    hipLaunchKernelGGL(k_pscan, dim3(40), dim3(256), 0, stream,
                       rowcnt, prior, plist, scal);
    hipLaunchKernelGGL(k_pfix, dim3(2500), dim3(256), 0, stream,
                       pboxes, gboxes, glab, clsval, valid, imgw, imgh,
                       plist, priorcol, colsum, scal);
    hipLaunchKernelGGL(k_surv, dim3(4), dim3(256), 0, stream,
                       rowcnt, picks, dkarr, colsum);
    for (int t = 0; t < LMAX; t++) {
        hipLaunchKernelGGL(k_iterA, dim3(1), dim3(1024), 0, stream,
                           colsum, rowcnt, infcnt, scal, t);
        hipLaunchKernelGGL(k_iterB, dim3(NG), dim3(256), 0, stream,
                           pboxes, gboxes, glab, clsval, valid, imgw, imgh,
                           infcnt, rowcnt, rowfirst, colsum, scal, t);
        hipLaunchKernelGGL(k_iterC, dim3(2500), dim3(256), 0, stream,
                           pboxes, gboxes, glab, clsval, valid, imgw, imgh,
                           plist, infcnt, priorcol, colsum, scal, t);
    }
    hipLaunchKernelGGL(k_final, dim3(40), dim3(256), 0, stream,
                       rowcnt, prior, priorcol, rowfirst, out);
}

// Round 5
// 195.863 us; speedup vs baseline: 4.2541x; 1.2439x over previous
//
#include <hip/hip_runtime.h>
#include <cfloat>
#include <cmath>

#define NP 10000
#define NG 1000
#define NC 80
#define LMAX 6

// scal[]: [12] anymulti (persistent), [14] nprior, [16+t] bodyran flag
#define S_MULTI 12
#define S_NPRI  14
#define S_BODY  16
#define RI_BIG  0x3fffffff

__device__ __forceinline__ bool lexless(float av, int ai, float bv, int bi) {
    return (av < bv) || (av == bv && ai < bi);
}

// Exact sequential +1e5 inflation (reference adds 1e5 once per loop iter).
__device__ __forceinline__ float inflate(float c, int k) {
    for (int q = 0; q < k; q++) c += 100000.0f;
    return c;
}

// Per-pair cost+iou from precomputed tables. Contraction OFF everywhere the
// value feeds comparisons, so all kernels agree bit-exactly.
// p: raw pred box. pn: p/factor. pi: {pcx,pcy,area_p,vadd}.
// g: raw gt box. cb: center bounds. Gn: g/factor. ga: area_g.
__device__ __forceinline__ void cost_iou(float4 p, float4 pn, float4 pi,
        float4 g, float4 cb, float4 Gn, float ga, float clsv,
        float& cc_out, float& iou_out) {
#pragma clang fp contract(off)
    float wx = fminf(p.z, g.z) - fmaxf(p.x, g.x); wx = fmaxf(wx, 0.0f);
    float wy = fminf(p.w, g.w) - fmaxf(p.y, g.y); wy = fmaxf(wy, 0.0f);
    float inter = wx * wy;
    float uni = pi.z + ga - inter;
    float iou = inter / fmaxf(uni, 1e-12f);
    float ex = fmaxf(p.z, g.z) - fminf(p.x, g.x); ex = fmaxf(ex, 0.0f);
    float ey = fmaxf(p.w, g.w) - fminf(p.y, g.y); ey = fmaxf(ey, 0.0f);
    float enc = ex * ey;
    float giou = iou - (enc - uni) / fmaxf(enc, 1e-12f);
    float l1 = ((fabsf(pn.x - Gn.x) + fabsf(pn.y - Gn.y))
                + fabsf(pn.z - Gn.z)) + fabsf(pn.w - Gn.w);
    float cc = clsv + l1 * 5.0f;
    cc = cc + (-giou * 2.0f);
    bool inb = (pi.x > g.x && pi.x < g.z && pi.y > g.y && pi.y < g.w);
    bool inc = (pi.x > cb.x && pi.x < cb.z && pi.y > cb.y && pi.y < cb.w);
    cc = cc + ((inb && inc) ? 0.0f : 100.0f);
    cc = cc + pi.w;
    cc_out = cc; iou_out = iou;
}

// ---------------------------------------------------------------------------
// Fused prep. Block ranges:
//  [0,40): init state
//  [40,197): cls table, 64 preds/block (LDS transpose, coalesced both ways)
//  [197,201): per-gt tables (cb, Gn, area)
//  [201,2701): wave-per-pred validity + per-pred tables
// ---------------------------------------------------------------------------
#define CLS_TI 64
#define PB_CLS0 40
#define PB_G0   197
#define PB_V0   201
__global__ __launch_bounds__(256) void k_prep(const float* __restrict__ logits,
        const float* __restrict__ pb, const float* __restrict__ gb,
        const int* __restrict__ imgw, const int* __restrict__ imgh,
        float* __restrict__ clsval, float4* __restrict__ pnorm,
        float4* __restrict__ pinfo, float4* __restrict__ gcb,
        float4* __restrict__ gnm, float* __restrict__ gar,
        int* rowcnt, int* rowfirst, int* rowiter, int* prior, int* priorcol,
        int* colsum, int* scal)
{
    __shared__ float sl[CLS_TI * (NC + 1)];
    int b = blockIdx.x;
    if (b < PB_CLS0) {
        int i = b * 256 + threadIdx.x;
        if (i < NP) {
            rowcnt[i] = 0; rowfirst[i] = 0x7fffffff; rowiter[i] = RI_BIG;
            prior[i] = 0; priorcol[i] = 0;
        }
        if (i < NG) colsum[i] = 0;
        if (i < 32) scal[i] = 0;
    } else if (b < PB_G0) {
        int i0 = (b - PB_CLS0) * CLS_TI;
        bool full = (i0 + CLS_TI) <= NP;
        if (full) {
            const float* src = logits + (size_t)i0 * NC;
            for (int e = threadIdx.x; e < CLS_TI * NC; e += 256) {
                int di = e / NC, c = e - di * NC;
                sl[di * (NC + 1) + c] = src[e];
            }
        } else {
            for (int e = threadIdx.x; e < CLS_TI * NC; e += 256) {
                int di = e / NC, c = e - di * NC;
                int i = i0 + di;
                sl[di * (NC + 1) + c] = (i < NP) ? logits[(size_t)i * NC + c] : 0.0f;
            }
        }
        __syncthreads();
        for (int e = threadIdx.x; e < CLS_TI * NC; e += 256) {
            int c = e >> 6, di = e & 63;
            int i = i0 + di;
            if (i >= NP) continue;
            float x = sl[di * (NC + 1) + c];
            float p = 1.0f / (1.0f + expf(-x));
            float neg = -log1pf(-(p - 1e-12f)) * 0.75f * (p * p);
            float om = 1.0f - p;
            float pos = -logf(p + 1e-12f) * 0.25f * (om * om);
            clsval[(size_t)c * NP + i] = (pos - neg) * 2.0f;   // * CLS_W
        }
    } else if (b < PB_V0) {
#pragma clang fp contract(off)
        int j = (b - PB_G0) * 256 + threadIdx.x;
        if (j < NG) {
            float fw = (float)imgw[0], fh = (float)imgh[0];
            float4 g = ((const float4*)gb)[j];
            float gcx = (g.x + g.z) * 0.5f, gcy = (g.y + g.w) * 0.5f;
            float gw = g.z - g.x, gh = g.w - g.y;
            float4 cb; cb.x = gcx - 2.5f * gw; cb.y = gcy - 2.5f * gh;
            cb.z = gcx + 2.5f * gw; cb.w = gcy + 2.5f * gh;
            gcb[j] = cb;
            float4 Gn; Gn.x = g.x / fw; Gn.y = g.y / fh; Gn.z = g.z / fw; Gn.w = g.w / fh;
            gnm[j] = Gn;
            gar[j] = (g.z - g.x) * (g.w - g.y);
        }
    } else {
#pragma clang fp contract(off)
        int wave = threadIdx.x >> 6;
        int lane = threadIdx.x & 63;
        int i = (b - PB_V0) * 4 + wave;
        if (i >= NP) return;
        float4 p = ((const float4*)pb)[i];
        float pcx = (p.x + p.z) * 0.5f, pcy = (p.y + p.w) * 0.5f;
        int vb = 0, vc = 0;
        const float4* gb4 = (const float4*)gb;
        for (int j = lane; j < NG; j += 64) {
            float4 g = gb4[j];
            vb |= (pcx > g.x && pcx < g.z && pcy > g.y && pcy < g.w) ? 1 : 0;
            float gcx = (g.x + g.z) * 0.5f, gcy = (g.y + g.w) * 0.5f;
            float gw = g.z - g.x, gh = g.w - g.y;
            vc |= (pcx > gcx - 2.5f * gw && pcx < gcx + 2.5f * gw &&
                   pcy > gcy - 2.5f * gh && pcy < gcy + 2.5f * gh) ? 1 : 0;
        }
        int any = (__any(vb) ? 1 : 0) | (__any(vc) ? 1 : 0);
        if (lane == 0) {
            float fw = (float)imgw[0], fh = (float)imgh[0];
            float4 pn; pn.x = p.x / fw; pn.y = p.y / fh; pn.z = p.z / fw; pn.w = p.w / fh;
            pnorm[i] = pn;
            float4 pi4; pi4.x = pcx; pi4.y = pcy;
            pi4.z = (p.z - p.x) * (p.w - p.y);
            pi4.w = any ? 0.0f : 10000.0f;
            pinfo[i] = pi4;
        }
    }
}

// ---------------------------------------------------------------------------
// Per-gt column: stream cost, top-5 min-cost (lex) + top-5 max-iou,
// dynamic_k, record picks + initial row assignments. Stride-7 LDS merge.
// ---------------------------------------------------------------------------
__global__ __launch_bounds__(256) void k_cost(
        const float* __restrict__ pb, const float* __restrict__ gb,
        const int* __restrict__ glab, const float* __restrict__ clsval,
        const float4* __restrict__ pnorm, const float4* __restrict__ pinfo,
        const float4* __restrict__ gcb, const float4* __restrict__ gnm,
        const float* __restrict__ gar,
        int* __restrict__ rowcnt, int* __restrict__ rowfirst,
        int* __restrict__ rowiter, int* __restrict__ picks,
        int* __restrict__ dkarr)
{
    __shared__ float s_cv[256 * 7];
    __shared__ int   s_ci[256 * 7];
    __shared__ float s_iv[256 * 7];

    int j = blockIdx.x;
    float4 g  = ((const float4*)gb)[j];
    float4 cb = gcb[j];
    float4 Gn = gnm[j];
    float  ga = gar[j];
    const float* clscol = clsval + (size_t)glab[j] * NP;
    const float4* pb4 = (const float4*)pb;

    float cv[5]; int ci[5]; float iv[5];
#pragma unroll
    for (int t = 0; t < 5; t++) { cv[t] = FLT_MAX; ci[t] = 0x7fffffff; iv[t] = -1.0f; }

    for (int i = threadIdx.x; i < NP; i += 256) {
        float cc, iou;
        cost_iou(pb4[i], pnorm[i], pinfo[i], g, cb, Gn, ga, clscol[i], cc, iou);

        if (lexless(cc, i, cv[4], ci[4])) {
            cv[4] = cc; ci[4] = i;
#pragma unroll
            for (int t = 4; t > 0; t--) {
                if (lexless(cv[t], ci[t], cv[t-1], ci[t-1])) {
                    float tv = cv[t]; cv[t] = cv[t-1]; cv[t-1] = tv;
                    int tx = ci[t]; ci[t] = ci[t-1]; ci[t-1] = tx;
                }
            }
        }
        if (iou > iv[4]) {
            iv[4] = iou;
#pragma unroll
            for (int t = 4; t > 0; t--) {
                if (iv[t] > iv[t-1]) { float tv = iv[t]; iv[t] = iv[t-1]; iv[t-1] = tv; }
            }
        }
    }

    int base = threadIdx.x * 7;
#pragma unroll
    for (int t = 0; t < 5; t++) { s_cv[base+t] = cv[t]; s_ci[base+t] = ci[t]; s_iv[base+t] = iv[t]; }
    s_cv[base+5] = FLT_MAX; s_ci[base+5] = 0x7fffffff; s_iv[base+5] = -2.0f;
    __syncthreads();

    for (int w = 128; w > 0; w >>= 1) {
        if (threadIdx.x < (unsigned)w) {
            int a = threadIdx.x * 7, bb = (threadIdx.x + w) * 7;
            float ov[5]; int oi[5]; float og[5];
            int pa = a, pbp = bb;
#pragma unroll
            for (int t = 0; t < 5; t++) {
                float A = s_cv[pa], B = s_cv[pbp];
                int Ai = s_ci[pa], Bi = s_ci[pbp];
                bool tA = (A < B) || (A == B && Ai <= Bi);
                if (tA) { ov[t] = A; oi[t] = Ai; pa++; } else { ov[t] = B; oi[t] = Bi; pbp++; }
            }
            int qa = a, qb = bb;
#pragma unroll
            for (int t = 0; t < 5; t++) {
                float A = s_iv[qa], B = s_iv[qb];
                if (A >= B) { og[t] = A; qa++; } else { og[t] = B; qb++; }
            }
#pragma unroll
            for (int t = 0; t < 5; t++) { s_cv[a+t] = ov[t]; s_ci[a+t] = oi[t]; s_iv[a+t] = og[t]; }
        }
        __syncthreads();
    }

    if (threadIdx.x == 0) {
        float s = (((s_iv[0] + s_iv[1]) + s_iv[2]) + s_iv[3]) + s_iv[4];
        int dk = (int)s;                 // astype(int32): truncation
        if (dk < 1) dk = 1;
        dkarr[j] = dk;
        for (int t = 0; t < dk; t++) {
            int r = s_ci[t];
            picks[j * 5 + t] = r;
            atomicAdd(&rowcnt[r], 1);
            atomicMin(&rowfirst[r], j);
            atomicMin(&rowiter[r], -1);   // initially matched
        }
    }
}

// ---------------------------------------------------------------------------
// Prior scan: rows with >1 initial assignment -> prior list.
// ---------------------------------------------------------------------------
__global__ __launch_bounds__(256) void k_pscan(const int* __restrict__ rowcnt,
        int* __restrict__ prior, int* __restrict__ plist, int* __restrict__ scal)
{
    int i = blockIdx.x * 256 + threadIdx.x;
    if (i >= NP) return;
    if (rowcnt[i] > 1) {
        prior[i] = 1;
        int idx = atomicAdd(&scal[S_NPRI], 1);
        plist[idx] = i;
    }
}

// ---------------------------------------------------------------------------
// Fused pfix + surv. Blocks [0,2500): per prior row, cooperative argmin over
// the row's (uninflated) cost -> priorcol, contribute to colsum.
// Blocks [2500,2504): surviving single-pick rows -> colsum.
// ---------------------------------------------------------------------------
__global__ __launch_bounds__(256) void k_pfixsurv(const float* __restrict__ pb,
        const float* __restrict__ gb, const int* __restrict__ glab,
        const float* __restrict__ clsval,
        const float4* __restrict__ pnorm, const float4* __restrict__ pinfo,
        const float4* __restrict__ gcb, const float4* __restrict__ gnm,
        const float* __restrict__ gar,
        const int* __restrict__ plist, int* __restrict__ priorcol,
        int* __restrict__ colsum, const int* __restrict__ scal,
        const int* __restrict__ rowcnt, const int* __restrict__ picks,
        const int* __restrict__ dkarr)
{
    int b = blockIdx.x;
    if (b >= 2500) {
        int j = (b - 2500) * 256 + threadIdx.x;
        if (j >= NG) return;
        int c = 0;
        int dk = dkarr[j];
        for (int t = 0; t < dk; t++) if (rowcnt[picks[j * 5 + t]] == 1) c++;
        if (c) atomicAdd(&colsum[j], c);
        return;
    }
    if (b >= scal[S_NPRI]) return;
    int row = plist[b];
    float4 p = ((const float4*)pb)[row];
    float4 pn = pnorm[row];
    float4 pi4 = pinfo[row];

    __shared__ float rv[256]; __shared__ int ri[256];
    float best = FLT_MAX; int bj = 0x7fffffff;
    for (int j = threadIdx.x; j < NG; j += 256) {
        float cc, iou;
        cost_iou(p, pn, pi4, ((const float4*)gb)[j], gcb[j], gnm[j], gar[j],
                 clsval[(size_t)glab[j] * NP + row], cc, iou);
        if (lexless(cc, j, best, bj)) { best = cc; bj = j; }
    }
    rv[threadIdx.x] = best; ri[threadIdx.x] = bj; __syncthreads();
    for (int w = 128; w > 0; w >>= 1) {
        if (threadIdx.x < (unsigned)w) {
            float ov = rv[threadIdx.x + w]; int oi = ri[threadIdx.x + w];
            if (lexless(ov, oi, rv[threadIdx.x], ri[threadIdx.x])) {
                rv[threadIdx.x] = ov; ri[threadIdx.x] = oi;
            }
        }
        __syncthreads();
    }
    if (threadIdx.x == 0) {
        priorcol[row] = ri[0];
        atomicAdd(&colsum[ri[0]], 1);
    }
}

// ---------------------------------------------------------------------------
// iterB: block per column; active iff colsum[j]==0. Argmin over UNINFLATED
// rows only (inflated rows strictly dominated: base <= ~10.2e3 < 1e5-50).
// rowiter < t  <=>  row matched before this iteration (inflated).
// Active blocks set bodyran[t]; collisions set persistent anymulti.
// ---------------------------------------------------------------------------
__global__ __launch_bounds__(256) void k_iterB(const float* __restrict__ pb,
        const float* __restrict__ gb, const int* __restrict__ glab,
        const float* __restrict__ clsval,
        const float4* __restrict__ pnorm, const float4* __restrict__ pinfo,
        const float4* __restrict__ gcb, const float4* __restrict__ gnm,
        const float* __restrict__ gar,
        int* __restrict__ rowiter, int* __restrict__ rowcnt,
        int* __restrict__ rowfirst, int* __restrict__ colsum,
        int* __restrict__ scal, int t)
{
    int j = blockIdx.x;
    if (colsum[j] != 0) return;
    if (threadIdx.x == 0) scal[S_BODY + t] = 1;   // body ran this iteration

    float4 g  = ((const float4*)gb)[j];
    float4 cb = gcb[j];
    float4 Gn = gnm[j];
    float  ga = gar[j];
    const float* clscol = clsval + (size_t)glab[j] * NP;
    const float4* pb4 = (const float4*)pb;

    __shared__ float rv[256]; __shared__ int ri[256];
    float best = FLT_MAX; int bi = 0x7fffffff;
    for (int i = threadIdx.x; i < NP; i += 256) {
        if (rowiter[i] < t) continue;   // inflated row: can never win
        float cc, iou;
        cost_iou(pb4[i], pnorm[i], pinfo[i], g, cb, Gn, ga, clscol[i], cc, iou);
        if (lexless(cc, i, best, bi)) { best = cc; bi = i; }
    }
    rv[threadIdx.x] = best; ri[threadIdx.x] = bi; __syncthreads();
    for (int w = 128; w > 0; w >>= 1) {
        if (threadIdx.x < (unsigned)w) {
            float ov = rv[threadIdx.x + w]; int oi = ri[threadIdx.x + w];
            if (lexless(ov, oi, rv[threadIdx.x], ri[threadIdx.x])) {
                rv[threadIdx.x] = ov; ri[threadIdx.x] = oi;
            }
        }
        __syncthreads();
    }
    if (threadIdx.x == 0) {
        int pos = ri[0];
        colsum[j] = 1;
        int old = atomicAdd(&rowcnt[pos], 1);
        if (old >= 1) scal[S_MULTI] = 1;   // same-iteration collision
        atomicMin(&rowfirst[pos], j);
        atomicMin(&rowiter[pos], t);       // matched at iteration t
    }
}

// ---------------------------------------------------------------------------
// iterC (m_fix): iff body ran at t && anymulti: each prior row re-argmins its
// inflated cost (exact sequential +1e5 per elapsed iteration — inflation is
// row-uniform but rounding can create ties, so replicate it).
// ---------------------------------------------------------------------------
__global__ __launch_bounds__(256) void k_iterC(const float* __restrict__ pb,
        const float* __restrict__ gb, const int* __restrict__ glab,
        const float* __restrict__ clsval,
        const float4* __restrict__ pnorm, const float4* __restrict__ pinfo,
        const float4* __restrict__ gcb, const float4* __restrict__ gnm,
        const float* __restrict__ gar,
        const int* __restrict__ plist, const int* __restrict__ rowiter,
        int* __restrict__ priorcol, int* __restrict__ colsum,
        int* __restrict__ scal, int t)
{
    if (scal[S_BODY + t] == 0 || scal[S_MULTI] == 0) return;
    if ((int)blockIdx.x >= scal[S_NPRI]) return;
    int row = plist[blockIdx.x];
    int k = t - rowiter[row]; if (k < 0) k = 0;   // prior rows: rowiter=-1 -> t+1
    float4 p = ((const float4*)pb)[row];
    float4 pn = pnorm[row];
    float4 pi4 = pinfo[row];

    __shared__ float rv[256]; __shared__ int ri[256];
    float best = FLT_MAX; int bj = 0x7fffffff;
    for (int j = threadIdx.x; j < NG; j += 256) {
        float cc, iou;
        cost_iou(p, pn, pi4, ((const float4*)gb)[j], gcb[j], gnm[j], gar[j],
                 clsval[(size_t)glab[j] * NP + row], cc, iou);
        float val = inflate(cc, k);
        if (lexless(val, j, best, bj)) { best = val; bj = j; }
    }
    rv[threadIdx.x] = best; ri[threadIdx.x] = bj; __syncthreads();
    for (int w = 128; w > 0; w >>= 1) {
        if (threadIdx.x < (unsigned)w) {
            float ov = rv[threadIdx.x + w]; int oi = ri[threadIdx.x + w];
            if (lexless(ov, oi, rv[threadIdx.x], ri[threadIdx.x])) {
                rv[threadIdx.x] = ov; ri[threadIdx.x] = oi;
            }
        }
        __syncthreads();
    }
    if (threadIdx.x == 0) {
        int nb = ri[0];
        int oldc = priorcol[row];
        if (nb != oldc) {
            atomicSub(&colsum[oldc], 1);
            atomicAdd(&colsum[nb], 1);
            priorcol[row] = nb;
        }
    }
}

// ---------------------------------------------------------------------------
// Final: fg = rowcnt>0; matched = priorcol (prior rows) else rowfirst. int32.
// ---------------------------------------------------------------------------
__global__ __launch_bounds__(256) void k_final(const int* __restrict__ rowcnt,
        const int* __restrict__ prior, const int* __restrict__ priorcol,
        const int* __restrict__ rowfirst, int* __restrict__ out)
{
    int i = blockIdx.x * 256 + threadIdx.x;
    if (i >= NP) return;
    int fg = rowcnt[i] > 0;
    out[i] = fg ? 1 : 0;
    out[NP + i] = fg ? (prior[i] ? priorcol[i] : rowfirst[i]) : 0;
}

extern "C" void kernel_launch(void* const* d_in, const int* in_sizes, int n_in,
                              void* d_out, int out_size, void* d_ws, size_t ws_size,
                              hipStream_t stream)
{
    (void)in_sizes; (void)n_in; (void)out_size; (void)ws_size;
    const float* logits = (const float*)d_in[0];
    const float* pboxes = (const float*)d_in[1];
    const float* gboxes = (const float*)d_in[2];
    const int*   glab   = (const int*)d_in[3];
    const int*   imgh   = (const int*)d_in[4];
    const int*   imgw   = (const int*)d_in[5];
    int* out = (int*)d_out;

    char* w = (char*)d_ws;
    float*  clsval  = (float*)(w);                    // 3,200,000
    float4* pnorm   = (float4*)(w + 3200000);         //   160,000
    float4* pinfo   = (float4*)(w + 3360000);         //   160,000
    float4* gcb     = (float4*)(w + 3520000);         //    16,000
    float4* gnm     = (float4*)(w + 3536000);         //    16,000
    float*  gar     = (float*)(w + 3552000);          //     4,000
    int* rowcnt     = (int*)(w + 3556000);            //    40,000
    int* rowfirst   = (int*)(w + 3596000);            //    40,000
    int* rowiter    = (int*)(w + 3636000);            //    40,000
    int* prior      = (int*)(w + 3676000);            //    40,000
    int* priorcol   = (int*)(w + 3716000);            //    40,000
    int* plist      = (int*)(w + 3756000);            //    40,000
    int* picks      = (int*)(w + 3796000);            //    20,000
    int* dkarr      = (int*)(w + 3816000);            //     4,000
    int* colsum     = (int*)(w + 3820000);            //     4,000
    int* scal       = (int*)(w + 3824000);            //       128

    hipLaunchKernelGGL(k_prep, dim3(2701), dim3(256), 0, stream,
                       logits, pboxes, gboxes, imgw, imgh,
                       clsval, pnorm, pinfo, gcb, gnm, gar,
                       rowcnt, rowfirst, rowiter, prior, priorcol, colsum, scal);
    hipLaunchKernelGGL(k_cost, dim3(NG), dim3(256), 0, stream,
                       pboxes, gboxes, glab, clsval, pnorm, pinfo, gcb, gnm, gar,
                       rowcnt, rowfirst, rowiter, picks, dkarr);
    hipLaunchKernelGGL(k_pscan, dim3(40), dim3(256), 0, stream,
                       rowcnt, prior, plist, scal);
    hipLaunchKernelGGL(k_pfixsurv, dim3(2504), dim3(256), 0, stream,
                       pboxes, gboxes, glab, clsval, pnorm, pinfo, gcb, gnm, gar,
                       plist, priorcol, colsum, scal, rowcnt, picks, dkarr);
    for (int t = 0; t < LMAX; t++) {
        hipLaunchKernelGGL(k_iterB, dim3(NG), dim3(256), 0, stream,
                           pboxes, gboxes, glab, clsval, pnorm, pinfo, gcb, gnm, gar,
                           rowiter, rowcnt, rowfirst, colsum, scal, t);
        hipLaunchKernelGGL(k_iterC, dim3(2500), dim3(256), 0, stream,
                           pboxes, gboxes, glab, clsval, pnorm, pinfo, gcb, gnm, gar,
                           plist, rowiter, priorcol, colsum, scal, t);
    }
    hipLaunchKernelGGL(k_final, dim3(40), dim3(256), 0, stream,
                       rowcnt, prior, priorcol, rowfirst, out);
}